// Round 3
// baseline (9294.103 us; speedup 1.0000x reference)
//
#include <hip/hip_runtime.h>
#include <hip/hip_bf16.h>
#include <math.h>

typedef __hip_bfloat16 bf16;

__device__ __forceinline__ float b2f(bf16 x) { return __bfloat162float(x); }
__device__ __forceinline__ bf16  f2b(float x) { return __float2bfloat16(x); }
__device__ __forceinline__ float bflo(unsigned u) { return __uint_as_float(u << 16); }
__device__ __forceinline__ float bfhi(unsigned u) { return __uint_as_float(u & 0xffff0000u); }
__device__ __forceinline__ float leaky(float x) { return x >= 0.0f ? x : 0.01f * x; }
// dual-dtype loader: f==1 -> float32 source, f==0 -> bf16 source
__device__ __forceinline__ float ldF(const void* p, size_t i, int f) {
  return f ? ((const float*)p)[i] : b2f(((const bf16*)p)[i]);
}

// dot of f32 LDS row with bf16 weight row (K multiple of 8, W 16B-aligned)
__device__ __forceinline__ float dotW(const float* __restrict__ A,
                                      const bf16* __restrict__ W, int K, float acc) {
  const uint4* wp = (const uint4*)W;
  int n8 = K >> 3;
#pragma unroll 4
  for (int k = 0; k < n8; ++k) {
    uint4 p = wp[k];
    const float* a = A + (k << 3);
    acc += a[0] * bflo(p.x) + a[1] * bfhi(p.x)
         + a[2] * bflo(p.y) + a[3] * bfhi(p.y)
         + a[4] * bflo(p.z) + a[5] * bfhi(p.z)
         + a[6] * bflo(p.w) + a[7] * bfhi(p.w);
  }
  return acc;
}

__device__ __forceinline__ void atomicMaxF(float* a, float v) {
  if (__float_as_uint(v) < 0x80000000u) atomicMax((int*)a, __float_as_int(v));
  else                                  atomicMin((unsigned int*)a, __float_as_uint(v));
}

__device__ __forceinline__ float wred64(float t) {
  for (int o = 32; o > 0; o >>= 1) t += __shfl_down(t, o, 64);
  return t;
}

// ---- dtype detector: low 16 bits of words are bf16 elements (exp sane) or f32 mantissa noise
__global__ void k_detect(const unsigned* __restrict__ w, int* __restrict__ flag) {
  __shared__ int cnt[256];
  unsigned x = w[threadIdx.x];
  unsigned ex = (x >> 7) & 0xFFu;
  cnt[threadIdx.x] = (ex >= 96u && ex <= 144u) ? 1 : 0;
  __syncthreads();
  for (int s = 128; s > 0; s >>= 1) {
    if (threadIdx.x < s) cnt[threadIdx.x] += cnt[threadIdx.x + s];
    __syncthreads();
  }
  if (threadIdx.x == 0) *flag = (cnt[0] < 128) ? 1 : 0;  // 1 = f32 inputs
}

// canonicalize a weight tensor to bf16
__global__ void k_cvt(const void* __restrict__ src, bf16* __restrict__ dst, int n,
                      const int* __restrict__ flagp) {
  int f = *flagp;
  int i = blockIdx.x * 256 + threadIdx.x;
  if (i < n) dst[i] = f ? f2b(((const float*)src)[i]) : ((const bf16*)src)[i];
}

__global__ void k_f2b(const float* __restrict__ src, bf16* __restrict__ dst, size_t n) {
  size_t i = (size_t)blockIdx.x * blockDim.x + threadIdx.x;
  size_t st = (size_t)gridDim.x * blockDim.x;
  for (; i < n; i += st) dst[i] = f2b(src[i]);
}

__global__ void k_fill(float* __restrict__ p, float v, size_t n) {
  size_t i = (size_t)blockIdx.x * blockDim.x + threadIdx.x;
  size_t s = (size_t)gridDim.x * blockDim.x;
  for (; i < n; i += s) p[i] = v;
}

// ---------------- phase 1 ----------------
__global__ __launch_bounds__(256)
void k_gemm_full(const void* __restrict__ A, const int* __restrict__ flagp,
                 const bf16* __restrict__ W, bf16* __restrict__ C) {
  int m = blockIdx.x, c = threadIdx.x;
  int f = *flagp;
  __shared__ float Ar[128];
  if (c < 128) Ar[c] = ldF(A, (size_t)m * 128 + c, f);
  __syncthreads();
  C[(size_t)m * 256 + c] = f2b(dotW(Ar, W + (size_t)c * 128, 128, 0.0f));
}

__global__ __launch_bounds__(256)
void k_egat_combine(const void* __restrict__ ef, const int* __restrict__ flagp,
                    const bf16* __restrict__ ni, const bf16* __restrict__ nj,
                    const bf16* __restrict__ Wfij, const bf16* __restrict__ bias,
                    const bf16* __restrict__ attn,
                    const int* __restrict__ src, const int* __restrict__ dst,
                    float* __restrict__ logits, bf16* __restrict__ fedge,
                    float* __restrict__ agg, float* __restrict__ cnt) {
  int e = blockIdx.x, c = threadIdx.x;
  int f = *flagp;
  __shared__ float Er[128];
  __shared__ float red[256];
  int s = src[e], t = dst[e];
  if (c < 128) Er[c] = ldF(ef, (size_t)e * 128 + c, f);
  __syncthreads();
  float v = dotW(Er, Wfij + (size_t)c * 128, 128, b2f(bias[c]));
  v += b2f(ni[(size_t)s * 256 + c]) + b2f(nj[(size_t)t * 256 + c]);
  v = leaky(v);
  float tt = wred64(v * b2f(attn[c]));
  if ((c & 63) == 0) logits[(size_t)e * 4 + (c >> 6)] = tt;
  red[c] = v;
  __syncthreads();
  if (c < 64) fedge[(size_t)e * 64 + c] = f2b(red[c] + red[c + 64] + red[c + 128] + red[c + 192]);
  if (c < 128) atomicAdd(&agg[(size_t)t * 128 + c], Er[c]);
  if (c == 0) atomicAdd(&cnt[t], 1.0f);
}

// h slice: concat(nfeats[128], aggB[128] bf16) @ Wslice[64,256].T + bias -> bf16 [M,64]
__global__ __launch_bounds__(256)
void k_gemm_h(const void* __restrict__ nf, const int* __restrict__ flagp,
              const bf16* __restrict__ aggB,
              const bf16* __restrict__ W, const bf16* __restrict__ bias,
              bf16* __restrict__ C, int M) {
  int d = threadIdx.x, r = threadIdx.y;
  int m = blockIdx.x * 4 + r;
  int f = *flagp;
  __shared__ float Ar[4][256];
  if (m < M) {
    Ar[r][d]       = ldF(nf, (size_t)m * 128 + d, f);
    Ar[r][d + 64]  = ldF(nf, (size_t)m * 128 + 64 + d, f);
    Ar[r][d + 128] = b2f(aggB[(size_t)m * 128 + d]);
    Ar[r][d + 192] = b2f(aggB[(size_t)m * 128 + 64 + d]);
  }
  __syncthreads();
  if (m >= M) return;
  C[(size_t)m * 64 + d] = f2b(dotW(Ar[r], W + (size_t)d * 256, 256, b2f(bias[d])));
}

// ---------------- generic slice GEMMs ----------------
__global__ __launch_bounds__(256)
void k_gemm_b64(const bf16* __restrict__ A, const bf16* __restrict__ W,
                bf16* __restrict__ C, int M) {
  int d = threadIdx.x, r = threadIdx.y;
  int m = blockIdx.x * 4 + r;
  __shared__ float Ar[4][64];
  if (m < M) Ar[r][d] = b2f(A[(size_t)m * 64 + d]);
  __syncthreads();
  if (m >= M) return;
  C[(size_t)m * 64 + d] = f2b(dotW(Ar[r], W + (size_t)d * 64, 64, 0.0f));
}

__global__ __launch_bounds__(256)
void k_gemm_m1(const bf16* __restrict__ fedge, const bf16* __restrict__ aggB,
               const bf16* __restrict__ W, const bf16* __restrict__ bias,
               bf16* __restrict__ C, int M) {
  int d = threadIdx.x, r = threadIdx.y;
  int m = blockIdx.x * 4 + r;
  __shared__ float Ar[4][128];
  if (m < M) {
    Ar[r][d]      = b2f(fedge[(size_t)m * 64 + d]);
    Ar[r][d + 64] = b2f(aggB[(size_t)m * 64 + d]);
  }
  __syncthreads();
  if (m >= M) return;
  C[(size_t)m * 64 + d] = f2b(dotW(Ar[r], W + (size_t)d * 128, 128, b2f(bias[d])));
}

__global__ __launch_bounds__(256)
void k_gemm_m2(const bf16* __restrict__ hn, const bf16* __restrict__ fedge,
               const int* __restrict__ src, const int* __restrict__ dst,
               const bf16* __restrict__ W, const bf16* __restrict__ bias,
               bf16* __restrict__ C, int M) {
  int d = threadIdx.x, r = threadIdx.y;
  int m = blockIdx.x * 4 + r;
  __shared__ float Ar[4][128];
  if (m < M) {
    int s = src[m], t = dst[m];
    Ar[r][d]      = b2f(hn[(size_t)s * 64 + d]) + b2f(hn[(size_t)t * 64 + d]);
    Ar[r][d + 64] = b2f(fedge[(size_t)m * 64 + d]);
  }
  __syncthreads();
  if (m >= M) return;
  C[(size_t)m * 64 + d] = f2b(dotW(Ar[r], W + (size_t)d * 128, 128, b2f(bias[d])));
}

// ---------------- per-head logit kernels ----------------
__global__ __launch_bounds__(256)
void k_lg_logit(const void* __restrict__ xf, const int* __restrict__ flagp,
                const bf16* __restrict__ lniH, const bf16* __restrict__ lnjH,
                const bf16* __restrict__ Wf, const bf16* __restrict__ bias,
                const bf16* __restrict__ attn,
                const int* __restrict__ lsrc, const int* __restrict__ ldst,
                float* __restrict__ lg, int EL) {
  int d = threadIdx.x, r = threadIdx.y;
  int el = blockIdx.x * 4 + r;
  int f = *flagp;
  __shared__ float X[4][64];
  if (el < EL) X[r][d] = ldF(xf, (size_t)el * 64 + d, f);
  __syncthreads();
  if (el >= EL) return;
  int s = lsrc[el], t = ldst[el];
  float v = dotW(X[r], Wf + (size_t)d * 64, 64, b2f(bias[d]));
  v += b2f(lniH[(size_t)s * 64 + d]) + b2f(lnjH[(size_t)t * 64 + d]);
  v = leaky(v);
  float tt = wred64(v * b2f(attn[d]));
  if (d == 0) lg[el] = tt;
}

__global__ __launch_bounds__(256)
void k_g_logit(const bf16* __restrict__ fedge, const bf16* __restrict__ gniH,
               const bf16* __restrict__ gnjH, const bf16* __restrict__ Wf,
               const bf16* __restrict__ bias, const bf16* __restrict__ attn,
               const int* __restrict__ src, const int* __restrict__ dst,
               float* __restrict__ lg, int E) {
  int d = threadIdx.x, r = threadIdx.y;
  int e = blockIdx.x * 4 + r;
  __shared__ float X[4][64];
  if (e < E) X[r][d] = b2f(fedge[(size_t)e * 64 + d]);
  __syncthreads();
  if (e >= E) return;
  int s = src[e], t = dst[e];
  float v = dotW(X[r], Wf + (size_t)d * 64, 64, b2f(bias[d]));
  v += b2f(gniH[(size_t)s * 64 + d]) + b2f(gnjH[(size_t)t * 64 + d]);
  v = leaky(v);
  float tt = wred64(v * b2f(attn[d]));
  if (d == 0) lg[e] = tt;
}

// ---------------- segment softmax ----------------
__global__ void k_seg_max4(const float* __restrict__ lg, const int* __restrict__ seg,
                           float* __restrict__ m, int nE) {
  int i = blockIdx.x * blockDim.x + threadIdx.x;
  if (i >= nE * 4) return;
  atomicMaxF(&m[(size_t)seg[i >> 2] * 4 + (i & 3)], lg[i]);
}
__global__ void k_seg_expsum4(float* __restrict__ lg, const int* __restrict__ seg,
                              const float* __restrict__ m, float* __restrict__ s, int nE) {
  int i = blockIdx.x * blockDim.x + threadIdx.x;
  if (i >= nE * 4) return;
  float ex = expf(lg[i] - m[(size_t)seg[i >> 2] * 4 + (i & 3)]);
  lg[i] = ex;
  atomicAdd(&s[(size_t)seg[i >> 2] * 4 + (i & 3)], ex);
}
__global__ void k_seg_norm4(float* __restrict__ lg, const int* __restrict__ seg,
                            const float* __restrict__ s, int nE) {
  int i = blockIdx.x * blockDim.x + threadIdx.x;
  if (i >= nE * 4) return;
  lg[i] /= s[(size_t)seg[i >> 2] * 4 + (i & 3)];
}
__global__ void k_seg_max1(const float* __restrict__ lg, const int* __restrict__ seg,
                           float* __restrict__ m, int nE) {
  int i = blockIdx.x * blockDim.x + threadIdx.x;
  if (i >= nE) return;
  atomicMaxF(&m[seg[i]], lg[i]);
}
__global__ void k_seg_expsum1(float* __restrict__ lg, const int* __restrict__ seg,
                              const float* __restrict__ m, float* __restrict__ s, int nE) {
  int i = blockIdx.x * blockDim.x + threadIdx.x;
  if (i >= nE) return;
  float ex = expf(lg[i] - m[seg[i]]);
  lg[i] = ex;
  atomicAdd(&s[seg[i]], ex);
}
__global__ void k_seg_norm1(float* __restrict__ lg, const int* __restrict__ seg,
                            const float* __restrict__ s, int nE) {
  int i = blockIdx.x * blockDim.x + threadIdx.x;
  if (i >= nE) return;
  lg[i] /= s[seg[i]];
}

__global__ void k_mean_div(float* __restrict__ agg, const float* __restrict__ cnt,
                           size_t n, int shift) {
  size_t i = (size_t)blockIdx.x * blockDim.x + threadIdx.x;
  size_t st = (size_t)gridDim.x * blockDim.x;
  for (; i < n; i += st) agg[i] /= fmaxf(cnt[i >> shift], 1.0f);
}

__global__ __launch_bounds__(256)
void k_aggx(const void* __restrict__ xf, const int* __restrict__ flagp,
            const int* __restrict__ ldst,
            float* __restrict__ aggx, float* __restrict__ cnt, int EL) {
  int d = threadIdx.x, r = threadIdx.y;
  int el = blockIdx.x * 4 + r;
  if (el >= EL) return;
  int f = *flagp;
  int t = ldst[el];
  atomicAdd(&aggx[(size_t)t * 64 + d], ldF(xf, (size_t)el * 64 + d, f));
  if (d == 0) atomicAdd(&cnt[t], 1.0f);
}

// ---------------- scatters ----------------
__global__ __launch_bounds__(256)
void k_scatter_att4(const bf16* __restrict__ P, const float* __restrict__ att,
                    const int* __restrict__ src, const int* __restrict__ dst,
                    float* __restrict__ acc, int E, int h) {
  int d = threadIdx.x, r = threadIdx.y;
  int e = blockIdx.x * 4 + r;
  if (e >= E) return;
  int s = src[e], t = dst[e];
  atomicAdd(&acc[(size_t)t * 64 + d], b2f(P[(size_t)s * 64 + d]) * att[(size_t)e * 4 + h]);
}
__global__ __launch_bounds__(256)
void k_scatter_att1(const bf16* __restrict__ P, const float* __restrict__ att,
                    const int* __restrict__ lsrc, const int* __restrict__ ldst,
                    float* __restrict__ acc, int EL) {
  int d = threadIdx.x, r = threadIdx.y;
  int el = blockIdx.x * 4 + r;
  if (el >= EL) return;
  int s = lsrc[el], t = ldst[el];
  atomicAdd(&acc[(size_t)t * 64 + d], b2f(P[(size_t)s * 64 + d]) * att[el]);
}
__global__ __launch_bounds__(256)
void k_scatter_plain(const bf16* __restrict__ P,
                     const int* __restrict__ lsrc, const int* __restrict__ ldst,
                     float* __restrict__ acc, int EL) {
  int d = threadIdx.x, r = threadIdx.y;
  int el = blockIdx.x * 4 + r;
  if (el >= EL) return;
  int s = lsrc[el], t = ldst[el];
  atomicAdd(&acc[(size_t)t * 64 + d], b2f(P[(size_t)s * 64 + d]));
}

// ---------------- epilogues ----------------
__global__ void k_addleaky(float* __restrict__ dst, const float* __restrict__ acc, size_t n) {
  size_t i = (size_t)blockIdx.x * blockDim.x + threadIdx.x;
  size_t st = (size_t)gridDim.x * blockDim.x;
  for (; i < n; i += st) dst[i] += leaky(acc[i]);
}
__global__ void k_add_ag(float* __restrict__ dst, const float* __restrict__ acc,
                         const float* __restrict__ ag, size_t n) {
  size_t i = (size_t)blockIdx.x * blockDim.x + threadIdx.x;
  size_t st = (size_t)gridDim.x * blockDim.x;
  for (; i < n; i += st) dst[i] += leaky(ag[i >> 6] * acc[i]);
}
__global__ void k_cast(void* __restrict__ out, const float* __restrict__ a, size_t n,
                       const int* __restrict__ flagp) {
  int f = *flagp;
  size_t i = (size_t)blockIdx.x * blockDim.x + threadIdx.x;
  size_t st = (size_t)gridDim.x * blockDim.x;
  for (; i < n; i += st) {
    if (f) ((float*)out)[i] = a[i];
    else   ((bf16*)out)[i] = f2b(a[i]);
  }
}

extern "C" void kernel_launch(void* const* d_in, const int* in_sizes, int n_in,
                              void* d_out, int out_size, void* d_ws, size_t ws_size,
                              hipStream_t stream) {
  const int* src  = (const int*)d_in[24];
  const int* dst  = (const int*)d_in[25];
  const int* lsrc = (const int*)d_in[26];
  const int* ldst = (const int*)d_in[27];

  const int N  = in_sizes[0] / 128;
  const int E  = in_sizes[24];
  const int EL = in_sizes[26];
  (void)n_in; (void)out_size; (void)ws_size;

  // ---- workspace arena (~167 MB) with lifetime overlays ----
  char* base = (char*)d_ws;
  size_t off = 0;
  auto alloc = [&](size_t bytes) -> char* {
    char* p = base + off;
    off = (off + bytes + 255) & ~(size_t)255;
    return p;
  };
  int* flag = (int*)alloc(256);
  // canonical bf16 weight arena (inputs 3..23)
  size_t wofs[28]; size_t wtot = 0;
  for (int i = 3; i <= 23; ++i) { wofs[i] = wtot; wtot += (size_t)((in_sizes[i] + 127) & ~127); }
  bf16* WA = (bf16*)alloc(wtot * 2);

  bf16* fedge = (bf16*)alloc((size_t)E * 64 * 2);   // persists p1->p3
  bf16* hnode = (bf16*)alloc((size_t)N * 64 * 2);   // persists p1->p3
  float* R    = (float*)alloc((size_t)E * 64 * 4);  // p1: agg/acc64/hacc; p2: aggx/acc64; p3: acc64
  size_t outB = (size_t)E * 64 * 4;
  size_t aggBbytes = (size_t)((N * 128 > E * 64) ? N * 128 : E * 64) * 2;
  size_t niB = (size_t)N * 256 * 2;
  size_t uB = outB + aggBbytes;
  if (2 * niB > uB) uB = 2 * niB;
  char* U = alloc(uB);
  float* outacc = (float*)U;                 // live p2 onward
  bf16*  aggB   = (bf16*)(U + outB);         // live after k_egat_combine
  bf16*  nibuf  = (bf16*)U;                  // p1 only
  bf16*  njbuf  = (bf16*)(U + niB);          // p1 only
  bf16* bufA = (bf16*)alloc((size_t)E * 64 * 2);
  bf16* bufB = (bf16*)alloc((size_t)E * 64 * 2);
  float* cntb = (float*)alloc((size_t)E * 4);
  size_t mN = (size_t)((N * 4 > E) ? N * 4 : E);
  float* mbuf = (float*)alloc(mN * 4);
  float* sbuf = (float*)alloc(mN * 4);
  float* logE4 = (float*)alloc((size_t)E * 4 * 4);
  float* logh  = (float*)alloc((size_t)EL * 4);

  dim3 blk(256);
  dim3 blk64x4(64, 4);
  auto fill = [&](float* p, float v, size_t n) {
    unsigned b = (unsigned)(((n + 255) / 256 < 4096) ? (n + 255) / 256 : 4096);
    k_fill<<<dim3(b), blk, 0, stream>>>(p, v, n);
  };
  const unsigned gE4 = (E + 3) / 4, gEL4 = (EL + 3) / 4, gN4 = (N + 3) / 4;
  const unsigned sE4 = (E * 4 + 255) / 256, sEL = (EL + 255) / 256, sE = (E + 255) / 256;

  // ---- dtype detect + weight canonicalization ----
  k_detect<<<dim3(1), blk, 0, stream>>>((const unsigned*)d_in[0], flag);
  for (int i = 3; i <= 23; ++i)
    k_cvt<<<dim3((in_sizes[i] + 255) / 256), blk, 0, stream>>>(d_in[i], WA + wofs[i],
                                                               in_sizes[i], flag);

  // ---------------- Phase 1: EGAT (full width) ----------------
  fill(R, 0.0f, (size_t)N * 128);              // agg
  fill(cntb, 0.0f, (size_t)N);
  fill(mbuf, -INFINITY, (size_t)N * 4);
  fill(sbuf, 0.0f, (size_t)N * 4);
  k_gemm_full<<<dim3(N), blk, 0, stream>>>(d_in[0], flag, WA + wofs[3], nibuf);
  k_gemm_full<<<dim3(N), blk, 0, stream>>>(d_in[0], flag, WA + wofs[4], njbuf);
  k_egat_combine<<<dim3(E), blk, 0, stream>>>(d_in[1], flag, nibuf, njbuf,
      WA + wofs[5], WA + wofs[9], WA + wofs[8], src, dst, logE4, fedge, R, cntb);
  k_seg_max4   <<<dim3(sE4), blk, 0, stream>>>(logE4, dst, mbuf, E);
  k_seg_expsum4<<<dim3(sE4), blk, 0, stream>>>(logE4, dst, mbuf, sbuf, E);
  k_seg_norm4  <<<dim3(sE4), blk, 0, stream>>>(logE4, dst, sbuf, E);
  k_mean_div<<<dim3(2048), blk, 0, stream>>>(R, cntb, (size_t)N * 128, 7);
  k_f2b<<<dim3(2048), blk, 0, stream>>>(R, aggB, (size_t)N * 128);   // njbuf dead now
  float* acc64p1 = R;                 // [0, N*64)
  float* hacc    = R + (size_t)N * 64;
  fill(hacc, 0.0f, (size_t)N * 64);
  for (int h = 0; h < 4; ++h) {
    k_gemm_h<<<dim3(gN4), blk64x4, 0, stream>>>(d_in[0], flag, aggB,
        WA + wofs[6] + (size_t)(h * 64) * 256, WA + wofs[7] + h * 64, bufA, N);
    fill(acc64p1, 0.0f, (size_t)N * 64);
    k_scatter_att4<<<dim3(gE4), blk64x4, 0, stream>>>(bufA, logE4, src, dst, acc64p1, E, h);
    k_addleaky<<<dim3(2048), blk, 0, stream>>>(hacc, acc64p1, (size_t)N * 64);
  }
  k_f2b<<<dim3(2048), blk, 0, stream>>>(hacc, hnode, (size_t)N * 64);

  // ---------------- Phase 2: line-graph branch (per head) ----------------
  fill(outacc, 0.0f, (size_t)E * 64);          // nibuf dead now
  fill(R, 0.0f, (size_t)E * 64);               // aggx
  fill(cntb, 0.0f, (size_t)E);
  k_aggx<<<dim3(gEL4), blk64x4, 0, stream>>>(d_in[2], flag, ldst, R, cntb, EL);
  k_mean_div<<<dim3(2048), blk, 0, stream>>>(R, cntb, (size_t)E * 64, 6);
  k_f2b<<<dim3(2048), blk, 0, stream>>>(R, aggB, (size_t)E * 64);
  for (int h = 0; h < 4; ++h) {
    k_gemm_b64<<<dim3(gE4), blk64x4, 0, stream>>>(fedge, WA + wofs[10] + h * 4096, bufA, E);
    k_gemm_b64<<<dim3(gE4), blk64x4, 0, stream>>>(fedge, WA + wofs[11] + h * 4096, bufB, E);
    fill(mbuf, -INFINITY, (size_t)E);
    fill(sbuf, 0.0f, (size_t)E);
    k_lg_logit<<<dim3(gEL4), blk64x4, 0, stream>>>(d_in[2], flag, bufA, bufB,
        WA + wofs[12] + h * 4096, WA + wofs[16] + h * 64, WA + wofs[15] + h * 64,
        lsrc, ldst, logh, EL);
    k_seg_max1   <<<dim3(sEL), blk, 0, stream>>>(logh, ldst, mbuf, EL);
    k_seg_expsum1<<<dim3(sEL), blk, 0, stream>>>(logh, ldst, mbuf, sbuf, EL);
    k_seg_norm1  <<<dim3(sEL), blk, 0, stream>>>(logh, ldst, sbuf, EL);
    k_gemm_m1<<<dim3(gE4), blk64x4, 0, stream>>>(fedge, aggB,
        WA + wofs[13] + (size_t)(h * 64) * 128, WA + wofs[14] + h * 64, bufA, E);
    fill(R, 0.0f, (size_t)E * 64);
    k_scatter_att1<<<dim3(gEL4), blk64x4, 0, stream>>>(bufA, logh, lsrc, ldst, R, EL);
    k_addleaky<<<dim3(2048), blk, 0, stream>>>(outacc, R, (size_t)E * 64);
  }

  // ---------------- Phase 3: graph branch (per head) ----------------
  bf16* gni = bufB;
  bf16* gnj = bufB + (size_t)N * 64;
  for (int h = 0; h < 4; ++h) {
    k_gemm_b64<<<dim3(gN4), blk64x4, 0, stream>>>(hnode, WA + wofs[17] + h * 4096, gni, N);
    k_gemm_b64<<<dim3(gN4), blk64x4, 0, stream>>>(hnode, WA + wofs[18] + h * 4096, gnj, N);
    fill(mbuf, -INFINITY, (size_t)N);
    fill(sbuf, 0.0f, (size_t)N);
    k_g_logit<<<dim3(gE4), blk64x4, 0, stream>>>(fedge, gni, gnj,
        WA + wofs[19] + h * 4096, WA + wofs[23] + h * 64, WA + wofs[22] + h * 64,
        src, dst, logh, E);
    k_seg_max1   <<<dim3(sE), blk, 0, stream>>>(logh, dst, mbuf, E);
    k_seg_expsum1<<<dim3(sE), blk, 0, stream>>>(logh, dst, mbuf, sbuf, E);
    k_seg_norm1  <<<dim3(sE), blk, 0, stream>>>(logh, dst, sbuf, E);
    k_gemm_m2<<<dim3(gE4), blk64x4, 0, stream>>>(hnode, fedge, src, dst,
        WA + wofs[20] + (size_t)(h * 64) * 128, WA + wofs[21] + h * 64, bufA, E);
    fill(R, 0.0f, (size_t)E * 64);
    k_scatter_plain<<<dim3(gEL4), blk64x4, 0, stream>>>(bufA, lsrc, ldst, R, EL);
    k_add_ag<<<dim3(2048), blk, 0, stream>>>(outacc, R, logh, (size_t)E * 64);
  }

  k_cast<<<dim3(2048), blk, 0, stream>>>(d_out, outacc, (size_t)E * 64, flag);
}

// Round 4
// 2900.429 us; speedup vs baseline: 3.2044x; 3.2044x over previous
//
#include <hip/hip_runtime.h>
#include <hip/hip_bf16.h>
#include <math.h>

typedef __hip_bfloat16 bf16;
typedef short bf16x8 __attribute__((ext_vector_type(8)));
typedef float f32x4 __attribute__((ext_vector_type(4)));

__device__ __forceinline__ float b2f(bf16 x) { return __bfloat162float(x); }
__device__ __forceinline__ bf16  f2b(float x) { return __float2bfloat16(x); }
__device__ __forceinline__ float leaky(float x) { return x >= 0.0f ? x : 0.01f * x; }
__device__ __forceinline__ float sb2f(short s) {
  return __uint_as_float(((unsigned)(unsigned short)s) << 16);
}
// f32 -> bf16 bits, round-to-nearest-even (finite inputs)
__device__ __forceinline__ short f2bs(float x) {
  unsigned u = __float_as_uint(x);
  u += 0x7FFFu + ((u >> 16) & 1u);
  return (short)(u >> 16);
}
// dual-dtype loader (scalar)
__device__ __forceinline__ float ldF(const void* p, size_t i, int f) {
  return f ? ((const float*)p)[i] : b2f(((const bf16*)p)[i]);
}
// load 8 contiguous elems as bf16x8 from bf16 (f=0) or f32 (f=1) row
__device__ __forceinline__ bf16x8 ldA8(const char* row, int k, int f) {
  if (!f) return *(const bf16x8*)(row + (size_t)k * 2);
  const float4* p = (const float4*)(row + (size_t)k * 4);
  float4 a = p[0], b = p[1];
  bf16x8 r;
  r[0] = f2bs(a.x); r[1] = f2bs(a.y); r[2] = f2bs(a.z); r[3] = f2bs(a.w);
  r[4] = f2bs(b.x); r[5] = f2bs(b.y); r[6] = f2bs(b.z); r[7] = f2bs(b.w);
  return r;
}
// gather-sum loader: bf16( base[s*K0+k..+7] + base[t*K0+k..+7] )
__device__ __forceinline__ bf16x8 ldA8sum(const bf16* base, int K0, int s, int t, int k) {
  bf16x8 u = *(const bf16x8*)(base + (size_t)s * K0 + k);
  bf16x8 v = *(const bf16x8*)(base + (size_t)t * K0 + k);
  bf16x8 r;
#pragma unroll
  for (int j = 0; j < 8; ++j) r[j] = f2bs(sb2f(u[j]) + sb2f(v[j]));
  return r;
}

__device__ __forceinline__ void atomicMaxF(float* a, float v) {
  if (__float_as_uint(v) < 0x80000000u) atomicMax((int*)a, __float_as_int(v));
  else                                  atomicMin((unsigned int*)a, __float_as_uint(v));
}

// ---- dtype detector ----
__global__ void k_detect(const unsigned* __restrict__ w, int* __restrict__ flag) {
  __shared__ int cnt[256];
  unsigned x = w[threadIdx.x];
  unsigned ex = (x >> 7) & 0xFFu;
  cnt[threadIdx.x] = (ex >= 96u && ex <= 144u) ? 1 : 0;
  __syncthreads();
  for (int s = 128; s > 0; s >>= 1) {
    if (threadIdx.x < s) cnt[threadIdx.x] += cnt[threadIdx.x + s];
    __syncthreads();
  }
  if (threadIdx.x == 0) *flag = (cnt[0] < 128) ? 1 : 0;  // 1 = f32 inputs
}

__global__ void k_cvt(const void* __restrict__ src, bf16* __restrict__ dst, int n,
                      const int* __restrict__ flagp) {
  int f = *flagp;
  int i = blockIdx.x * 256 + threadIdx.x;
  if (i < n) dst[i] = f ? f2b(((const float*)src)[i]) : ((const bf16*)src)[i];
}

__global__ void k_f2b(const float* __restrict__ src, bf16* __restrict__ dst, size_t n) {
  size_t i = (size_t)blockIdx.x * blockDim.x + threadIdx.x;
  size_t st = (size_t)gridDim.x * blockDim.x;
  for (; i < n; i += st) dst[i] = f2b(src[i]);
}

__global__ void k_fill(float* __restrict__ p, float v, size_t n) {
  size_t i = (size_t)blockIdx.x * blockDim.x + threadIdx.x;
  size_t s = (size_t)gridDim.x * blockDim.x;
  for (; i < n; i += s) p[i] = v;
}

// =================== MFMA GEMM: C[M,64] = A[M,Ktot] @ W[64,Ktot]^T (+bias) ===================
// A = concat(A0[:K0], A1[:Ktot-K0]); per-pointer dtype mode: 0=bf16, 1=f32, 2=*flagp.
// If gs!=null: A0 row m = base[gs[m]] + base[gd[m]] (bf16 base, row length K0).
__global__ __launch_bounds__(256)
void k_mgemm(const void* __restrict__ A0, int m0mode, int K0,
             const void* __restrict__ A1, int m1mode, int Ktot,
             const bf16* __restrict__ W, const bf16* __restrict__ bias,
             bf16* __restrict__ C, int M,
             const int* __restrict__ gs, const int* __restrict__ gd,
             const int* __restrict__ flagp) {
  int tid = threadIdx.x;
  int w = tid >> 6, lane = tid & 63, l15 = lane & 15, q = lane >> 4;
  int fl = *flagp;
  int f0 = (m0mode == 2) ? fl : m0mode;
  int f1 = (m1mode == 2) ? fl : m1mode;
  int m0 = blockIdx.x * 64 + w * 16;
  int mA = m0 + l15; if (mA > M - 1) mA = M - 1;
  int sA = 0, tA = 0;
  const char* rowA0 = nullptr;
  if (gs) { sA = gs[mA]; tA = gd[mA]; }
  else rowA0 = (const char*)A0 + (size_t)mA * K0 * (f0 ? 4 : 2);
  const char* rowA1 = A1 ? (const char*)A1 + (size_t)mA * (Ktot - K0) * (f1 ? 4 : 2) : nullptr;

  f32x4 acc[4] = {{0,0,0,0},{0,0,0,0},{0,0,0,0},{0,0,0,0}};
  for (int k = q * 8; k < Ktot; k += 32) {
    bf16x8 a;
    if (k < K0) a = gs ? ldA8sum((const bf16*)A0, K0, sA, tA, k) : ldA8(rowA0, k, f0);
    else        a = ldA8(rowA1, k - K0, f1);
    const bf16* wb = W + (size_t)l15 * Ktot + k;
#pragma unroll
    for (int t = 0; t < 4; ++t)
      acc[t] = __builtin_amdgcn_mfma_f32_16x16x32_bf16(
          a, *(const bf16x8*)(wb + (size_t)(t * 16) * Ktot), acc[t], 0, 0, 0);
  }
#pragma unroll
  for (int t = 0; t < 4; ++t) {
    int col = t * 16 + l15;
    float bv = bias ? b2f(bias[col]) : 0.0f;
#pragma unroll
    for (int r = 0; r < 4; ++r) {
      int m = m0 + q * 4 + r;
      if (m < M) C[(size_t)m * 64 + col] = f2b(acc[t][r] + bv);
    }
  }
}

// ====== fused GEMM + gather + leaky + attn-logit (+optional f32 row accumulation) ======
// v[m,col] = leaky( (A@W^T)[m,col] + bias[col] + G1[gi[m]][col] + G2[gj[m]][col] )
// logit[m*logStride+logOff] = sum_col v*attn[col];  if accR: accR[m*64+col] += v
__global__ __launch_bounds__(256)
void k_mcomb(const void* __restrict__ A, int mode, int K,
             const bf16* __restrict__ W, const bf16* __restrict__ bias,
             const bf16* __restrict__ attn,
             const bf16* __restrict__ G1, const bf16* __restrict__ G2,
             const int* __restrict__ gi, const int* __restrict__ gj,
             float* __restrict__ logit, int logStride, int logOff,
             float* __restrict__ accR, int M, const int* __restrict__ flagp) {
  int tid = threadIdx.x;
  int w = tid >> 6, lane = tid & 63, l15 = lane & 15, q = lane >> 4;
  int f = (mode == 2) ? *flagp : mode;
  int m0 = blockIdx.x * 64 + w * 16;
  int mA = m0 + l15; if (mA > M - 1) mA = M - 1;
  const char* rowA = (const char*)A + (size_t)mA * K * (f ? 4 : 2);

  f32x4 acc[4] = {{0,0,0,0},{0,0,0,0},{0,0,0,0},{0,0,0,0}};
  for (int k = q * 8; k < K; k += 32) {
    bf16x8 a = ldA8(rowA, k, f);
    const bf16* wb = W + (size_t)l15 * K + k;
#pragma unroll
    for (int t = 0; t < 4; ++t)
      acc[t] = __builtin_amdgcn_mfma_f32_16x16x32_bf16(
          a, *(const bf16x8*)(wb + (size_t)(t * 16) * K), acc[t], 0, 0, 0);
  }
  float attv[4], bsv[4];
#pragma unroll
  for (int t = 0; t < 4; ++t) { attv[t] = b2f(attn[t*16+l15]); bsv[t] = b2f(bias[t*16+l15]); }
  float part[4];
#pragma unroll
  for (int r = 0; r < 4; ++r) {
    int m = m0 + q * 4 + r;
    bool ok = m < M; int mc = ok ? m : M - 1;
    int s = gi[mc], d2 = gj[mc];
    const bf16* g1 = G1 + (size_t)s * 64;
    const bf16* g2 = G2 + (size_t)d2 * 64;
    float p = 0.0f;
#pragma unroll
    for (int t = 0; t < 4; ++t) {
      int col = t * 16 + l15;
      float v = acc[t][r] + bsv[t] + b2f(g1[col]) + b2f(g2[col]);
      v = leaky(v);
      p += v * attv[t];
      if (ok && accR) accR[(size_t)m * 64 + col] += v;
    }
    part[r] = p;
  }
#pragma unroll
  for (int o = 1; o < 16; o <<= 1) {
#pragma unroll
    for (int r = 0; r < 4; ++r) part[r] += __shfl_xor(part[r], o, 64);
  }
  if (l15 == 0) {
#pragma unroll
    for (int r = 0; r < 4; ++r) {
      int m = m0 + q * 4 + r;
      if (m < M) logit[(size_t)m * logStride + logOff] = part[r];
    }
  }
}

// ---------------- segment softmax ----------------
__global__ void k_seg_max4(const float* __restrict__ lg, const int* __restrict__ seg,
                           float* __restrict__ m, int nE) {
  int i = blockIdx.x * blockDim.x + threadIdx.x;
  if (i >= nE * 4) return;
  atomicMaxF(&m[(size_t)seg[i >> 2] * 4 + (i & 3)], lg[i]);
}
__global__ void k_seg_expsum4(float* __restrict__ lg, const int* __restrict__ seg,
                              const float* __restrict__ m, float* __restrict__ s, int nE) {
  int i = blockIdx.x * blockDim.x + threadIdx.x;
  if (i >= nE * 4) return;
  float ex = expf(lg[i] - m[(size_t)seg[i >> 2] * 4 + (i & 3)]);
  lg[i] = ex;
  atomicAdd(&s[(size_t)seg[i >> 2] * 4 + (i & 3)], ex);
}
__global__ void k_seg_norm4(float* __restrict__ lg, const int* __restrict__ seg,
                            const float* __restrict__ s, int nE) {
  int i = blockIdx.x * blockDim.x + threadIdx.x;
  if (i >= nE * 4) return;
  lg[i] /= s[(size_t)seg[i >> 2] * 4 + (i & 3)];
}
__global__ void k_seg_max1(const float* __restrict__ lg, const int* __restrict__ seg,
                           float* __restrict__ m, int nE) {
  int i = blockIdx.x * blockDim.x + threadIdx.x;
  if (i >= nE) return;
  atomicMaxF(&m[seg[i]], lg[i]);
}
__global__ void k_seg_expsum1(float* __restrict__ lg, const int* __restrict__ seg,
                              const float* __restrict__ m, float* __restrict__ s, int nE) {
  int i = blockIdx.x * blockDim.x + threadIdx.x;
  if (i >= nE) return;
  float ex = expf(lg[i] - m[seg[i]]);
  lg[i] = ex;
  atomicAdd(&s[seg[i]], ex);
}
__global__ void k_seg_norm1(float* __restrict__ lg, const int* __restrict__ seg,
                            const float* __restrict__ s, int nE) {
  int i = blockIdx.x * blockDim.x + threadIdx.x;
  if (i >= nE) return;
  lg[i] /= s[seg[i]];
}

__global__ void k_mean_div(float* __restrict__ agg, const float* __restrict__ cnt,
                           size_t n, int shift) {
  size_t i = (size_t)blockIdx.x * blockDim.x + threadIdx.x;
  size_t st = (size_t)gridDim.x * blockDim.x;
  for (; i < n; i += st) agg[i] /= fmaxf(cnt[i >> shift], 1.0f);
}

// agg of 128-wide edge feats into dst nodes (+count)
__global__ __launch_bounds__(256)
void k_agg128(const void* __restrict__ ef, const int* __restrict__ flagp,
              const int* __restrict__ dst, float* __restrict__ agg,
              float* __restrict__ cnt, int E) {
  int d = threadIdx.x, r = threadIdx.y;
  int e = blockIdx.x * 2 + r;
  if (e >= E) return;
  int f = *flagp;
  int t = dst[e];
  atomicAdd(&agg[(size_t)t * 128 + d], ldF(ef, (size_t)e * 128 + d, f));
  if (d == 0) atomicAdd(&cnt[t], 1.0f);
}
// agg of 64-wide angle feats into bond nodes (+count)
__global__ __launch_bounds__(256)
void k_aggx(const void* __restrict__ xf, const int* __restrict__ flagp,
            const int* __restrict__ ldst,
            float* __restrict__ aggx, float* __restrict__ cnt, int EL) {
  int d = threadIdx.x, r = threadIdx.y;
  int el = blockIdx.x * 4 + r;
  if (el >= EL) return;
  int f = *flagp;
  int t = ldst[el];
  atomicAdd(&aggx[(size_t)t * 64 + d], ldF(xf, (size_t)el * 64 + d, f));
  if (d == 0) atomicAdd(&cnt[t], 1.0f);
}

// ---------------- scatters ----------------
__global__ __launch_bounds__(256)
void k_scatter_att4(const bf16* __restrict__ P, const float* __restrict__ att,
                    const int* __restrict__ src, const int* __restrict__ dst,
                    float* __restrict__ acc, int E, int h) {
  int d = threadIdx.x, r = threadIdx.y;
  int e = blockIdx.x * 4 + r;
  if (e >= E) return;
  int s = src[e], t = dst[e];
  atomicAdd(&acc[(size_t)t * 64 + d], b2f(P[(size_t)s * 64 + d]) * att[(size_t)e * 4 + h]);
}
__global__ __launch_bounds__(256)
void k_scatter_att1(const bf16* __restrict__ P, const float* __restrict__ att,
                    const int* __restrict__ lsrc, const int* __restrict__ ldst,
                    float* __restrict__ acc, int EL) {
  int d = threadIdx.x, r = threadIdx.y;
  int el = blockIdx.x * 4 + r;
  if (el >= EL) return;
  int s = lsrc[el], t = ldst[el];
  atomicAdd(&acc[(size_t)t * 64 + d], b2f(P[(size_t)s * 64 + d]) * att[el]);
}
__global__ __launch_bounds__(256)
void k_scatter_plain(const bf16* __restrict__ P,
                     const int* __restrict__ lsrc, const int* __restrict__ ldst,
                     float* __restrict__ acc, int EL) {
  int d = threadIdx.x, r = threadIdx.y;
  int el = blockIdx.x * 4 + r;
  if (el >= EL) return;
  int s = lsrc[el], t = ldst[el];
  atomicAdd(&acc[(size_t)t * 64 + d], b2f(P[(size_t)s * 64 + d]));
}

// ---------------- epilogues ----------------
__global__ void k_addleaky(float* __restrict__ dst, const float* __restrict__ acc, size_t n) {
  size_t i = (size_t)blockIdx.x * blockDim.x + threadIdx.x;
  size_t st = (size_t)gridDim.x * blockDim.x;
  for (; i < n; i += st) dst[i] += leaky(acc[i]);
}
__global__ void k_add_ag(float* __restrict__ dst, const float* __restrict__ acc,
                         const float* __restrict__ ag, size_t n) {
  size_t i = (size_t)blockIdx.x * blockDim.x + threadIdx.x;
  size_t st = (size_t)gridDim.x * blockDim.x;
  for (; i < n; i += st) dst[i] += leaky(ag[i >> 6] * acc[i]);
}
__global__ void k_cast(void* __restrict__ out, const float* __restrict__ a, size_t n,
                       const int* __restrict__ flagp) {
  int f = *flagp;
  size_t i = (size_t)blockIdx.x * blockDim.x + threadIdx.x;
  size_t st = (size_t)gridDim.x * blockDim.x;
  for (; i < n; i += st) {
    if (f) ((float*)out)[i] = a[i];
    else   ((bf16*)out)[i] = f2b(a[i]);
  }
}

extern "C" void kernel_launch(void* const* d_in, const int* in_sizes, int n_in,
                              void* d_out, int out_size, void* d_ws, size_t ws_size,
                              hipStream_t stream) {
  const int* src  = (const int*)d_in[24];
  const int* dst  = (const int*)d_in[25];
  const int* lsrc = (const int*)d_in[26];
  const int* ldst = (const int*)d_in[27];

  const int N  = in_sizes[0] / 128;
  const int E  = in_sizes[24];
  const int EL = in_sizes[26];
  (void)n_in; (void)out_size; (void)ws_size;

  // ---- workspace (~167 MB, same footprint class as round 3 which passed) ----
  char* base = (char*)d_ws;
  size_t off = 0;
  auto alloc = [&](size_t bytes) -> char* {
    char* p = base + off;
    off = (off + bytes + 255) & ~(size_t)255;
    return p;
  };
  int* flag = (int*)alloc(256);
  size_t wofs[28]; size_t wtot = 0;
  for (int i = 3; i <= 23; ++i) { wofs[i] = wtot; wtot += (size_t)((in_sizes[i] + 127) & ~127); }
  bf16* WA = (bf16*)alloc(wtot * 2);

  bf16*  fedge  = (bf16*)alloc((size_t)E * 64 * 2);   // P1 -> P3
  bf16*  hnode  = (bf16*)alloc((size_t)N * 64 * 2);   // P1 -> P3
  float* R      = (float*)alloc((size_t)E * 64 * 4);  // fedge-acc / scatter-acc / aggx
  float* outacc = (float*)alloc((size_t)E * 64 * 4);  // P1: agg[N,128]f; P2+: output acc
  bf16*  aggB   = (bf16*)alloc((size_t)E * 64 * 2);   // agg/aggx bf16 (>= N*128 elems)
  bf16*  SA     = (bf16*)alloc((size_t)E * 64 * 2);   // ni_h/h_h | lni/m1 | gni+gnj
  bf16*  SB     = (bf16*)alloc((size_t)E * 64 * 2);   // nj_h     | lnj    | m2
  float* logE4  = (float*)alloc((size_t)E * 4 * 4);
  float* logh   = (float*)alloc((size_t)EL * 4);
  float* mbuf   = (float*)alloc((size_t)(N * 4) * 4);
  float* sbuf   = (float*)alloc((size_t)(N * 4) * 4);
  float* cntb   = (float*)alloc((size_t)E * 4);

  dim3 blk(256);
  dim3 blk64x4(64, 4);
  dim3 blk128x2(128, 2);
  auto fill = [&](float* p, float v, size_t n) {
    unsigned b = (unsigned)(((n + 255) / 256 < 4096) ? (n + 255) / 256 : 4096);
    k_fill<<<dim3(b), blk, 0, stream>>>(p, v, n);
  };
  const unsigned tN = (N + 63) / 64, tEg = (E + 63) / 64, tELg = (EL + 63) / 64;
  const unsigned gE4 = (E + 3) / 4, gEL4 = (EL + 3) / 4;
  const unsigned sE4 = (E * 4 + 255) / 256, sEL = (EL + 255) / 256, sE = (E + 255) / 256;

  // ---- dtype detect + weight canonicalization ----
  k_detect<<<dim3(1), blk, 0, stream>>>((const unsigned*)d_in[0], flag);
  for (int i = 3; i <= 23; ++i)
    k_cvt<<<dim3((in_sizes[i] + 255) / 256), blk, 0, stream>>>(d_in[i], WA + wofs[i],
                                                               in_sizes[i], flag);

  // ================= Phase 1: EGAT =================
  fill(outacc, 0.0f, (size_t)N * 128);   // agg
  fill(cntb, 0.0f, (size_t)N);
  k_agg128<<<dim3((E + 1) / 2), blk128x2, 0, stream>>>(d_in[1], flag, dst, outacc, cntb, E);
  fill(R, 0.0f, (size_t)E * 64);         // fedge accumulator
  fill(mbuf, -INFINITY, (size_t)N * 4);
  fill(sbuf, 0.0f, (size_t)N * 4);
  for (int h = 0; h < 4; ++h) {
    k_mgemm<<<dim3(tN), blk, 0, stream>>>(d_in[0], 2, 128, nullptr, 0, 128,
        WA + wofs[3] + h * 8192, nullptr, SA, N, nullptr, nullptr, flag);
    k_mgemm<<<dim3(tN), blk, 0, stream>>>(d_in[0], 2, 128, nullptr, 0, 128,
        WA + wofs[4] + h * 8192, nullptr, SB, N, nullptr, nullptr, flag);
    k_mcomb<<<dim3(tEg), blk, 0, stream>>>(d_in[1], 2, 128,
        WA + wofs[5] + h * 8192, WA + wofs[9] + h * 64, WA + wofs[8] + h * 64,
        SA, SB, src, dst, logE4, 4, h, R, E, flag);
  }
  k_seg_max4   <<<dim3(sE4), blk, 0, stream>>>(logE4, dst, mbuf, E);
  k_seg_expsum4<<<dim3(sE4), blk, 0, stream>>>(logE4, dst, mbuf, sbuf, E);
  k_seg_norm4  <<<dim3(sE4), blk, 0, stream>>>(logE4, dst, sbuf, E);
  k_mean_div<<<dim3(2048), blk, 0, stream>>>(outacc, cntb, (size_t)N * 128, 7);
  k_f2b<<<dim3(2048), blk, 0, stream>>>(outacc, aggB, (size_t)N * 128);
  k_f2b<<<dim3(2048), blk, 0, stream>>>(R, fedge, (size_t)E * 64);
  float* hacc = R + (size_t)N * 64;
  fill(hacc, 0.0f, (size_t)N * 64);
  for (int h = 0; h < 4; ++h) {
    k_mgemm<<<dim3(tN), blk, 0, stream>>>(d_in[0], 2, 128, aggB, 0, 256,
        WA + wofs[6] + h * 16384, WA + wofs[7] + h * 64, SA, N, nullptr, nullptr, flag);
    fill(R, 0.0f, (size_t)N * 64);
    k_scatter_att4<<<dim3(gE4), blk64x4, 0, stream>>>(SA, logE4, src, dst, R, E, h);
    k_addleaky<<<dim3(2048), blk, 0, stream>>>(hacc, R, (size_t)N * 64);
  }
  k_f2b<<<dim3(2048), blk, 0, stream>>>(hacc, hnode, (size_t)N * 64);

  // ================= Phase 2: line-graph branch =================
  fill(outacc, 0.0f, (size_t)E * 64);
  fill(R, 0.0f, (size_t)E * 64);
  fill(cntb, 0.0f, (size_t)E);
  k_aggx<<<dim3(gEL4), blk64x4, 0, stream>>>(d_in[2], flag, ldst, R, cntb, EL);
  k_mean_div<<<dim3(2048), blk, 0, stream>>>(R, cntb, (size_t)E * 64, 6);
  k_f2b<<<dim3(2048), blk, 0, stream>>>(R, aggB, (size_t)E * 64);
  for (int h = 0; h < 4; ++h) {
    k_mgemm<<<dim3(tEg), blk, 0, stream>>>(fedge, 0, 64, nullptr, 0, 64,
        WA + wofs[10] + h * 4096, nullptr, SA, E, nullptr, nullptr, flag);
    k_mgemm<<<dim3(tEg), blk, 0, stream>>>(fedge, 0, 64, nullptr, 0, 64,
        WA + wofs[11] + h * 4096, nullptr, SB, E, nullptr, nullptr, flag);
    fill(mbuf, -INFINITY, (size_t)E);
    fill(sbuf, 0.0f, (size_t)E);
    k_mcomb<<<dim3(tELg), blk, 0, stream>>>(d_in[2], 2, 64,
        WA + wofs[12] + h * 4096, WA + wofs[16] + h * 64, WA + wofs[15] + h * 64,
        SA, SB, lsrc, ldst, logh, 1, 0, nullptr, EL, flag);
    k_seg_max1   <<<dim3(sEL), blk, 0, stream>>>(logh, ldst, mbuf, EL);
    k_seg_expsum1<<<dim3(sEL), blk, 0, stream>>>(logh, ldst, mbuf, sbuf, EL);
    k_seg_norm1  <<<dim3(sEL), blk, 0, stream>>>(logh, ldst, sbuf, EL);
    k_mgemm<<<dim3(tEg), blk, 0, stream>>>(fedge, 0, 64, aggB, 0, 128,
        WA + wofs[13] + h * 8192, WA + wofs[14] + h * 64, SA, E, nullptr, nullptr, flag);
    fill(R, 0.0f, (size_t)E * 64);
    k_scatter_att1<<<dim3(gEL4), blk64x4, 0, stream>>>(SA, logh, lsrc, ldst, R, EL);
    k_addleaky<<<dim3(2048), blk, 0, stream>>>(outacc, R, (size_t)E * 64);
  }

  // ================= Phase 3: graph branch =================
  bf16* gni = SA;
  bf16* gnj = SA + (size_t)N * 64;
  for (int h = 0; h < 4; ++h) {
    k_mgemm<<<dim3(tN), blk, 0, stream>>>(hnode, 0, 64, nullptr, 0, 64,
        WA + wofs[17] + h * 4096, nullptr, gni, N, nullptr, nullptr, flag);
    k_mgemm<<<dim3(tN), blk, 0, stream>>>(hnode, 0, 64, nullptr, 0, 64,
        WA + wofs[18] + h * 4096, nullptr, gnj, N, nullptr, nullptr, flag);
    fill(mbuf, -INFINITY, (size_t)N);
    fill(sbuf, 0.0f, (size_t)N);
    k_mcomb<<<dim3(tEg), blk, 0, stream>>>(fedge, 0, 64,
        WA + wofs[19] + h * 4096, WA + wofs[23] + h * 64, WA + wofs[22] + h * 64,
        gni, gnj, src, dst, logh, 1, 0, nullptr, E, flag);
    k_seg_max1   <<<dim3(sE), blk, 0, stream>>>(logh, dst, mbuf, E);
    k_seg_expsum1<<<dim3(sE), blk, 0, stream>>>(logh, dst, mbuf, sbuf, E);
    k_seg_norm1  <<<dim3(sE), blk, 0, stream>>>(logh, dst, sbuf, E);
    k_mgemm<<<dim3(tEg), blk, 0, stream>>>(hnode, 0, 64, fedge, 0, 128,
        WA + wofs[20] + h * 8192, WA + wofs[21] + h * 64, SB, E, src, dst, flag);
    fill(R, 0.0f, (size_t)E * 64);
    k_scatter_plain<<<dim3(gEL4), blk64x4, 0, stream>>>(SB, lsrc, ldst, R, EL);
    k_add_ag<<<dim3(2048), blk, 0, stream>>>(outacc, R, logh, (size_t)E * 64);
  }

  k_cast<<<dim3(2048), blk, 0, stream>>>(d_out, outacc, (size_t)E * 64, flag);
}

// Round 5
// 2390.972 us; speedup vs baseline: 3.8872x; 1.2131x over previous
//
#include <hip/hip_runtime.h>
#include <hip/hip_bf16.h>
#include <math.h>

typedef __hip_bfloat16 bf16;
typedef short bf16x8 __attribute__((ext_vector_type(8)));
typedef float f32x4 __attribute__((ext_vector_type(4)));

__device__ __forceinline__ float b2f(bf16 x) { return __bfloat162float(x); }
__device__ __forceinline__ bf16  f2b(float x) { return __float2bfloat16(x); }
__device__ __forceinline__ float leaky(float x) { return x >= 0.0f ? x : 0.01f * x; }
__device__ __forceinline__ float sb2f(short s) {
  return __uint_as_float(((unsigned)(unsigned short)s) << 16);
}
__device__ __forceinline__ short f2bs(float x) {
  unsigned u = __float_as_uint(x);
  u += 0x7FFFu + ((u >> 16) & 1u);
  return (short)(u >> 16);
}
__device__ __forceinline__ float ldF(const void* p, size_t i, int f) {
  return f ? ((const float*)p)[i] : b2f(((const bf16*)p)[i]);
}
__device__ __forceinline__ bf16x8 ldA8(const char* row, int k, int f) {
  if (!f) return *(const bf16x8*)(row + (size_t)k * 2);
  const float4* p = (const float4*)(row + (size_t)k * 4);
  float4 a = p[0], b = p[1];
  bf16x8 r;
  r[0] = f2bs(a.x); r[1] = f2bs(a.y); r[2] = f2bs(a.z); r[3] = f2bs(a.w);
  r[4] = f2bs(b.x); r[5] = f2bs(b.y); r[6] = f2bs(b.z); r[7] = f2bs(b.w);
  return r;
}
__device__ __forceinline__ bf16x8 ldA8sum(const bf16* base, int K0, int s, int t, int k) {
  bf16x8 u = *(const bf16x8*)(base + (size_t)s * K0 + k);
  bf16x8 v = *(const bf16x8*)(base + (size_t)t * K0 + k);
  bf16x8 r;
#pragma unroll
  for (int j = 0; j < 8; ++j) r[j] = f2bs(sb2f(u[j]) + sb2f(v[j]));
  return r;
}
__device__ __forceinline__ void atomicMaxF(float* a, float v) {
  if (__float_as_uint(v) < 0x80000000u) atomicMax((int*)a, __float_as_int(v));
  else                                  atomicMin((unsigned int*)a, __float_as_uint(v));
}

// ---- dtype detector ----
__global__ void k_detect(const unsigned* __restrict__ w, int* __restrict__ flag) {
  __shared__ int cnt[256];
  unsigned x = w[threadIdx.x];
  unsigned ex = (x >> 7) & 0xFFu;
  cnt[threadIdx.x] = (ex >= 96u && ex <= 144u) ? 1 : 0;
  __syncthreads();
  for (int s = 128; s > 0; s >>= 1) {
    if (threadIdx.x < s) cnt[threadIdx.x] += cnt[threadIdx.x + s];
    __syncthreads();
  }
  if (threadIdx.x == 0) *flag = (cnt[0] < 128) ? 1 : 0;  // 1 = f32 inputs
}

// ---- all-weights canonicalization in one launch ----
struct WArgs { const void* src[21]; int beg[22]; int len[21]; };
__global__ void k_cvt_all(WArgs wa, bf16* __restrict__ dst, int total,
                          const int* __restrict__ flagp) {
  int f = *flagp;
  for (int i = blockIdx.x * 256 + threadIdx.x; i < total; i += gridDim.x * 256) {
    int t = 0;
    while (t < 20 && i >= wa.beg[t + 1]) ++t;
    int loc = i - wa.beg[t];
    bf16 v = f2b(0.0f);
    if (loc < wa.len[t])
      v = f ? f2b(((const float*)wa.src[t])[loc]) : ((const bf16*)wa.src[t])[loc];
    dst[i] = v;
  }
}

__global__ void k_fill(float* __restrict__ p, float v, size_t n) {
  size_t i = (size_t)blockIdx.x * blockDim.x + threadIdx.x;
  size_t s = (size_t)gridDim.x * blockDim.x;
  for (; i < n; i += s) p[i] = v;
}
__global__ void k_fill2(float* __restrict__ a, float va, size_t na,
                        float* __restrict__ b, float vb, size_t nb) {
  size_t i = (size_t)blockIdx.x * blockDim.x + threadIdx.x;
  size_t s = (size_t)gridDim.x * blockDim.x;
  for (; i < na + nb; i += s) {
    if (i < na) a[i] = va; else b[i - na] = vb;
  }
}
__global__ void k_izero(int* __restrict__ p, int n) {
  int i = blockIdx.x * 256 + threadIdx.x;
  for (; i < n; i += gridDim.x * 256) p[i] = 0;
}

// ---------------- CSR build ----------------
__global__ void k_hist(const int* __restrict__ seg, int* __restrict__ deg, int n) {
  int i = blockIdx.x * 256 + threadIdx.x;
  if (i < n) atomicAdd(&deg[seg[i]], 1);
}
// single-block exclusive-prefix -> rp[0..n], 1024 threads, 8 elems/thread/chunk
__global__ __launch_bounds__(1024)
void k_scan(const int* __restrict__ deg, int* __restrict__ rp, int n) {
  __shared__ int sh[1024];
  __shared__ int carry;
  int tid = threadIdx.x;
  if (tid == 0) { carry = 0; rp[0] = 0; }
  __syncthreads();
  for (int base = 0; base < n; base += 1024 * 8) {
    int idx0 = base + tid * 8;
    int v[8]; int s = 0;
#pragma unroll
    for (int j = 0; j < 8; ++j) { v[j] = (idx0 + j < n) ? deg[idx0 + j] : 0; s += v[j]; }
    sh[tid] = s;
    __syncthreads();
    for (int o = 1; o < 1024; o <<= 1) {
      int t = (tid >= o) ? sh[tid - o] : 0;
      __syncthreads();
      sh[tid] += t;
      __syncthreads();
    }
    int run = carry + sh[tid] - s;
#pragma unroll
    for (int j = 0; j < 8; ++j) { run += v[j]; if (idx0 + j < n) rp[idx0 + j + 1] = run; }
    int tot = sh[1023];
    __syncthreads();
    if (tid == 0) carry += tot;
    __syncthreads();
  }
}
__global__ void k_slot(const int* __restrict__ seg, const int* __restrict__ rp,
                       int* __restrict__ cur, int* __restrict__ eid, int n) {
  int i = blockIdx.x * 256 + threadIdx.x;
  if (i >= n) return;
  int t = seg[i];
  int p = atomicAdd(&cur[t], 1);
  eid[rp[t] + p] = i;
}

// ---------------- gather-mean: out[row,:w] = mean of X[eid] rows ----------------
__global__ void k_gmean(const void* __restrict__ X, int mode,
                        const int* __restrict__ rp, const int* __restrict__ eid,
                        bf16* __restrict__ out, int n, int width,
                        const int* __restrict__ flagp) {
  int f = (mode == 2) ? *flagp : mode;
  int d = threadIdx.x;
  int row = blockIdx.x * blockDim.y + threadIdx.y;
  if (row >= n) return;
  int b = rp[row], e = rp[row + 1];
  float s = 0.0f;
  for (int j = b; j < e; ++j) s += ldF(X, (size_t)eid[j] * width + d, f);
  out[(size_t)row * width + d] = f2b(s / fmaxf((float)(e - b), 1.0f));
}

// =================== MFMA GEMM: C[.,colofs+0..63] = A @ Wh^T (+bias) ===================
__global__ __launch_bounds__(256)
void k_mgemm(const void* __restrict__ A0, int m0mode, int K0,
             const void* __restrict__ A1, int m1mode, int Ktot,
             const bf16* __restrict__ W, int whs, const bf16* __restrict__ bias,
             bf16* __restrict__ C, int cs, int M,
             const int* __restrict__ gs, const int* __restrict__ gd,
             const int* __restrict__ flagp) {
  int tid = threadIdx.x;
  int w = tid >> 6, lane = tid & 63, l15 = lane & 15, q = lane >> 4;
  int h = blockIdx.y;
  int fl = *flagp;
  int f0 = (m0mode == 2) ? fl : m0mode;
  int f1 = (m1mode == 2) ? fl : m1mode;
  const bf16* Wh = W + (size_t)h * whs;
  int colofs = h * 64;
  int m0 = blockIdx.x * 64 + w * 16;
  int mA = m0 + l15; if (mA > M - 1) mA = M - 1;
  int sA = 0, tA = 0;
  const char* rowA0 = nullptr;
  if (gs) { sA = gs[mA]; tA = gd[mA]; }
  else rowA0 = (const char*)A0 + (size_t)mA * K0 * (f0 ? 4 : 2);
  const char* rowA1 = A1 ? (const char*)A1 + (size_t)mA * (Ktot - K0) * (f1 ? 4 : 2) : nullptr;

  f32x4 acc[4] = {{0,0,0,0},{0,0,0,0},{0,0,0,0},{0,0,0,0}};
  for (int k = q * 8; k < Ktot; k += 32) {
    bf16x8 a;
    if (k < K0) a = gs ? ldA8sum((const bf16*)A0, K0, sA, tA, k) : ldA8(rowA0, k, f0);
    else        a = ldA8(rowA1, k - K0, f1);
    const bf16* wb = Wh + (size_t)l15 * Ktot + k;
#pragma unroll
    for (int t = 0; t < 4; ++t)
      acc[t] = __builtin_amdgcn_mfma_f32_16x16x32_bf16(
          a, *(const bf16x8*)(wb + (size_t)(t * 16) * Ktot), acc[t], 0, 0, 0);
  }
#pragma unroll
  for (int t = 0; t < 4; ++t) {
    int col = t * 16 + l15;
    float bv = bias ? b2f(bias[colofs + col]) : 0.0f;
#pragma unroll
    for (int r = 0; r < 4; ++r) {
      int m = m0 + q * 4 + r;
      if (m < M) C[(size_t)m * cs + colofs + col] = f2b(acc[t][r] + bv);
    }
  }
}

// ---- dual-output GEMM (shared A): C1 = A@W1h^T, C2 = A@W2h^T (no bias) ----
__global__ __launch_bounds__(256)
void k_mgemm2(const void* __restrict__ A, int mode, int K,
              const bf16* __restrict__ W1, const bf16* __restrict__ W2, int whs,
              bf16* __restrict__ C1, bf16* __restrict__ C2, int cs, int M,
              const int* __restrict__ flagp) {
  int tid = threadIdx.x;
  int w = tid >> 6, lane = tid & 63, l15 = lane & 15, q = lane >> 4;
  int h = blockIdx.y;
  int f = (mode == 2) ? *flagp : mode;
  const bf16* W1h = W1 + (size_t)h * whs;
  const bf16* W2h = W2 + (size_t)h * whs;
  int colofs = h * 64;
  int m0 = blockIdx.x * 64 + w * 16;
  int mA = m0 + l15; if (mA > M - 1) mA = M - 1;
  const char* rowA = (const char*)A + (size_t)mA * K * (f ? 4 : 2);

  f32x4 a1[4] = {{0,0,0,0},{0,0,0,0},{0,0,0,0},{0,0,0,0}};
  f32x4 a2[4] = {{0,0,0,0},{0,0,0,0},{0,0,0,0},{0,0,0,0}};
  for (int k = q * 8; k < K; k += 32) {
    bf16x8 a = ldA8(rowA, k, f);
    const bf16* w1 = W1h + (size_t)l15 * K + k;
    const bf16* w2 = W2h + (size_t)l15 * K + k;
#pragma unroll
    for (int t = 0; t < 4; ++t) {
      a1[t] = __builtin_amdgcn_mfma_f32_16x16x32_bf16(
          a, *(const bf16x8*)(w1 + (size_t)(t * 16) * K), a1[t], 0, 0, 0);
      a2[t] = __builtin_amdgcn_mfma_f32_16x16x32_bf16(
          a, *(const bf16x8*)(w2 + (size_t)(t * 16) * K), a2[t], 0, 0, 0);
    }
  }
#pragma unroll
  for (int t = 0; t < 4; ++t) {
    int col = t * 16 + l15;
#pragma unroll
    for (int r = 0; r < 4; ++r) {
      int m = m0 + q * 4 + r;
      if (m < M) {
        C1[(size_t)m * cs + colofs + col] = f2b(a1[t][r]);
        C2[(size_t)m * cs + colofs + col] = f2b(a2[t][r]);
      }
    }
  }
}

// ====== all-heads fused combine: logits[M,4] (+optional fedge=sum_h v) ======
template<int NK>
__global__ __launch_bounds__(256)
void k_mcomb4(const void* __restrict__ A, int mode,
              const bf16* __restrict__ W, int whs,
              const bf16* __restrict__ bias, const bf16* __restrict__ attn,
              const bf16* __restrict__ G1, const bf16* __restrict__ G2, int gstr,
              const int* __restrict__ gi, const int* __restrict__ gj,
              float* __restrict__ lg4, bf16* __restrict__ fout,
              int M, const int* __restrict__ flagp) {
  constexpr int K = NK * 32;
  int tid = threadIdx.x;
  int w = tid >> 6, lane = tid & 63, l15 = lane & 15, q = lane >> 4;
  int f = (mode == 2) ? *flagp : mode;
  int m0 = blockIdx.x * 64 + w * 16;
  int mA = m0 + l15; if (mA > M - 1) mA = M - 1;
  const char* rowA = (const char*)A + (size_t)mA * K * (f ? 4 : 2);
  bf16x8 af[NK];
#pragma unroll
  for (int i = 0; i < NK; ++i) af[i] = ldA8(rowA, q * 8 + 32 * i, f);
  int sIdx[4], dIdx[4]; bool okr[4];
#pragma unroll
  for (int r = 0; r < 4; ++r) {
    int m = m0 + q * 4 + r;
    okr[r] = m < M; int mc = okr[r] ? m : M - 1;
    sIdx[r] = gi[mc]; dIdx[r] = gj[mc];
  }
  f32x4 fs[4] = {{0,0,0,0},{0,0,0,0},{0,0,0,0},{0,0,0,0}};
  for (int h = 0; h < 4; ++h) {
    const bf16* Wh = W + (size_t)h * whs;
    f32x4 acc[4] = {{0,0,0,0},{0,0,0,0},{0,0,0,0},{0,0,0,0}};
#pragma unroll
    for (int i = 0; i < NK; ++i) {
      const bf16* wb = Wh + (size_t)l15 * K + q * 8 + 32 * i;
#pragma unroll
      for (int t = 0; t < 4; ++t)
        acc[t] = __builtin_amdgcn_mfma_f32_16x16x32_bf16(
            af[i], *(const bf16x8*)(wb + (size_t)(t * 16) * K), acc[t], 0, 0, 0);
    }
    float part[4];
#pragma unroll
    for (int r = 0; r < 4; ++r) {
      const bf16* g1 = G1 + (size_t)sIdx[r] * gstr + h * 64;
      const bf16* g2 = G2 + (size_t)dIdx[r] * gstr + h * 64;
      float p = 0.0f;
#pragma unroll
      for (int t = 0; t < 4; ++t) {
        int col = t * 16 + l15;
        float v = acc[t][r] + b2f(bias[h * 64 + col]) + b2f(g1[col]) + b2f(g2[col]);
        v = leaky(v);
        p += v * b2f(attn[h * 64 + col]);
        fs[t][r] += v;
      }
      part[r] = p;
    }
#pragma unroll
    for (int o = 1; o < 16; o <<= 1)
#pragma unroll
      for (int r = 0; r < 4; ++r) part[r] += __shfl_xor(part[r], o, 64);
    if (l15 == 0) {
#pragma unroll
      for (int r = 0; r < 4; ++r)
        if (okr[r]) lg4[(size_t)(m0 + q * 4 + r) * 4 + h] = part[r];
    }
  }
  if (fout) {
#pragma unroll
    for (int t = 0; t < 4; ++t) {
      int col = t * 16 + l15;
#pragma unroll
      for (int r = 0; r < 4; ++r)
        if (okr[r]) fout[(size_t)(m0 + q * 4 + r) * 64 + col] = f2b(fs[t][r]);
    }
  }
}

// ---- per-head fused combine (P2 line graph): logit[M] ----
__global__ __launch_bounds__(256)
void k_mcomb(const void* __restrict__ A, int mode, int K,
             const bf16* __restrict__ W, const bf16* __restrict__ bias,
             const bf16* __restrict__ attn,
             const bf16* __restrict__ G1, const bf16* __restrict__ G2, int gstr,
             const int* __restrict__ gi, const int* __restrict__ gj,
             float* __restrict__ lg, int M, const int* __restrict__ flagp) {
  int tid = threadIdx.x;
  int w = tid >> 6, lane = tid & 63, l15 = lane & 15, q = lane >> 4;
  int f = (mode == 2) ? *flagp : mode;
  int m0 = blockIdx.x * 64 + w * 16;
  int mA = m0 + l15; if (mA > M - 1) mA = M - 1;
  const char* rowA = (const char*)A + (size_t)mA * K * (f ? 4 : 2);
  f32x4 acc[4] = {{0,0,0,0},{0,0,0,0},{0,0,0,0},{0,0,0,0}};
  for (int k = q * 8; k < K; k += 32) {
    bf16x8 a = ldA8(rowA, k, f);
    const bf16* wb = W + (size_t)l15 * K + k;
#pragma unroll
    for (int t = 0; t < 4; ++t)
      acc[t] = __builtin_amdgcn_mfma_f32_16x16x32_bf16(
          a, *(const bf16x8*)(wb + (size_t)(t * 16) * K), acc[t], 0, 0, 0);
  }
  float attv[4], bsv[4];
#pragma unroll
  for (int t = 0; t < 4; ++t) { attv[t] = b2f(attn[t*16+l15]); bsv[t] = b2f(bias[t*16+l15]); }
  float part[4];
#pragma unroll
  for (int r = 0; r < 4; ++r) {
    int m = m0 + q * 4 + r;
    bool ok = m < M; int mc = ok ? m : M - 1;
    const bf16* g1 = G1 + (size_t)gi[mc] * gstr;
    const bf16* g2 = G2 + (size_t)gj[mc] * gstr;
    float p = 0.0f;
#pragma unroll
    for (int t = 0; t < 4; ++t) {
      int col = t * 16 + l15;
      float v = acc[t][r] + bsv[t] + b2f(g1[col]) + b2f(g2[col]);
      p += leaky(v) * attv[t];
    }
    part[r] = p;
  }
#pragma unroll
  for (int o = 1; o < 16; o <<= 1)
#pragma unroll
    for (int r = 0; r < 4; ++r) part[r] += __shfl_xor(part[r], o, 64);
  if (l15 == 0) {
#pragma unroll
    for (int r = 0; r < 4; ++r) {
      int m = m0 + q * 4 + r;
      if (m < M) lg[m] = part[r];
    }
  }
}

// ---------------- segment softmax (max + expsum; norm folded into consumers) ----------------
__global__ void k_seg_max4(const float* __restrict__ lg, const int* __restrict__ seg,
                           float* __restrict__ m, int nE) {
  int i = blockIdx.x * blockDim.x + threadIdx.x;
  if (i >= nE * 4) return;
  atomicMaxF(&m[(size_t)seg[i >> 2] * 4 + (i & 3)], lg[i]);
}
__global__ void k_seg_expsum4(float* __restrict__ lg, const int* __restrict__ seg,
                              const float* __restrict__ m, float* __restrict__ s, int nE) {
  int i = blockIdx.x * blockDim.x + threadIdx.x;
  if (i >= nE * 4) return;
  float ex = expf(lg[i] - m[(size_t)seg[i >> 2] * 4 + (i & 3)]);
  lg[i] = ex;
  atomicAdd(&s[(size_t)seg[i >> 2] * 4 + (i & 3)], ex);
}
__global__ void k_seg_max1(const float* __restrict__ lg, const int* __restrict__ seg,
                           float* __restrict__ m, int nE) {
  int i = blockIdx.x * blockDim.x + threadIdx.x;
  if (i >= nE) return;
  atomicMaxF(&m[seg[i]], lg[i]);
}
__global__ void k_seg_expsum1(float* __restrict__ lg, const int* __restrict__ seg,
                              const float* __restrict__ m, float* __restrict__ s, int nE) {
  int i = blockIdx.x * blockDim.x + threadIdx.x;
  if (i >= nE) return;
  float ex = expf(lg[i] - m[seg[i]]);
  lg[i] = ex;
  atomicAdd(&s[seg[i]], ex);
}

// ---- P1 epilogue: hnode[n,d] = bf16( sum_h leaky( (sum_e H[src[e],h*64+d]*lg4[e,h]) / s4[n,h] ) )
__global__ void k_ghnode(const bf16* __restrict__ H, const float* __restrict__ lg4,
                         const float* __restrict__ s4,
                         const int* __restrict__ rp, const int* __restrict__ eid,
                         const int* __restrict__ src, bf16* __restrict__ hnode, int N) {
  int d = threadIdx.x;
  int n = blockIdx.x * 4 + threadIdx.y;
  if (n >= N) return;
  int b = rp[n], e = rp[n + 1];
  float o = 0.0f;
  for (int h = 0; h < 4; ++h) {
    float s = 0.0f;
    for (int j = b; j < e; ++j) {
      int ed = eid[j];
      s += b2f(H[(size_t)src[ed] * 256 + h * 64 + d]) * lg4[(size_t)ed * 4 + h];
    }
    if (e > b) o += leaky(s / s4[(size_t)n * 4 + h]);
  }
  hnode[(size_t)n * 64 + d] = f2b(o);
}

// ---- P2 epilogue: out[t,d] (=|+=) leaky( (sum_el M1[lsrc[el],d]*lgE[el]) / sE[t] )
__global__ void k_gout2(const bf16* __restrict__ M1, const float* __restrict__ lgE,
                        const float* __restrict__ sE,
                        const int* __restrict__ rp, const int* __restrict__ eid,
                        const int* __restrict__ lsrc,
                        float* __restrict__ out, int E, int first) {
  int d = threadIdx.x;
  int t = blockIdx.x * 4 + threadIdx.y;
  if (t >= E) return;
  int b = rp[t], e = rp[t + 1];
  float s = 0.0f;
  for (int j = b; j < e; ++j) {
    int el = eid[j];
    s += b2f(M1[(size_t)lsrc[el] * 64 + d]) * lgE[el];
  }
  float val = (e > b) ? leaky(s / sE[t]) : 0.0f;
  if (first) out[(size_t)t * 64 + d] = val;
  else       out[(size_t)t * 64 + d] += val;
}

// ---- P3 epilogue: out[t,d] += leaky( a_g[t,h] * sum_el M2[lsrc[el],d] )
__global__ void k_gout3(const bf16* __restrict__ M2, const float* __restrict__ lg4,
                        const float* __restrict__ s4, const int* __restrict__ dstE,
                        const int* __restrict__ rp, const int* __restrict__ eid,
                        const int* __restrict__ lsrc,
                        float* __restrict__ out, int E, int h) {
  int d = threadIdx.x;
  int t = blockIdx.x * 4 + threadIdx.y;
  if (t >= E) return;
  int b = rp[t], e = rp[t + 1];
  float s = 0.0f;
  for (int j = b; j < e; ++j) s += b2f(M2[(size_t)lsrc[eid[j]] * 64 + d]);
  float a = lg4[(size_t)t * 4 + h] / s4[(size_t)dstE[t] * 4 + h];
  out[(size_t)t * 64 + d] += leaky(a * s);
}

__global__ void k_cast(void* __restrict__ out, const float* __restrict__ a, size_t n,
                       const int* __restrict__ flagp) {
  int f = *flagp;
  size_t i = (size_t)blockIdx.x * blockDim.x + threadIdx.x;
  size_t st = (size_t)gridDim.x * blockDim.x;
  for (; i < n; i += st) {
    if (f) ((float*)out)[i] = a[i];
    else   ((bf16*)out)[i] = f2b(a[i]);
  }
}

extern "C" void kernel_launch(void* const* d_in, const int* in_sizes, int n_in,
                              void* d_out, int out_size, void* d_ws, size_t ws_size,
                              hipStream_t stream) {
  const int* src  = (const int*)d_in[24];
  const int* dst  = (const int*)d_in[25];
  const int* lsrc = (const int*)d_in[26];
  const int* ldst = (const int*)d_in[27];

  const int N  = in_sizes[0] / 128;
  const int E  = in_sizes[24];
  const int EL = in_sizes[26];
  (void)n_in; (void)out_size; (void)ws_size;

  // ---- workspace (~145 MB, under proven 167 MB) ----
  char* base = (char*)d_ws;
  size_t off = 0;
  auto alloc = [&](size_t bytes) -> char* {
    char* p = base + off;
    off = (off + bytes + 255) & ~(size_t)255;
    return p;
  };
  int* flag = (int*)alloc(256);
  size_t wofs[28]; size_t wtot = 0;
  for (int i = 3; i <= 23; ++i) { wofs[i] = wtot; wtot += (size_t)((in_sizes[i] + 127) & ~127); }
  bf16* WA = (bf16*)alloc(wtot * 2);

  int*   tmpi  = (int*)alloc((size_t)2 * E * 4);        // deg | cur
  int*   rpN   = (int*)alloc((size_t)(N + 1) * 4);
  int*   eidN  = (int*)alloc((size_t)E * 4);
  int*   rpE   = (int*)alloc((size_t)(E + 1) * 4);
  int*   eidEL = (int*)alloc((size_t)EL * 4);
  bf16*  fedge = (bf16*)alloc((size_t)E * 64 * 2);      // P1 -> P3
  bf16*  hnode = (bf16*)alloc((size_t)N * 64 * 2);      // P1 -> P3
  float* outacc= (float*)alloc((size_t)E * 64 * 4);     // P2+ output accumulator
  bf16*  aggB  = (bf16*)alloc((size_t)E * 64 * 2);      // P1 agg[N,128] / P2 aggx[E,64]
  bf16*  SA    = (bf16*)alloc((size_t)N * 256 * 2 > (size_t)E * 64 * 2
                              ? (size_t)N * 256 * 2 : (size_t)E * 64 * 2);
  bf16*  SB    = (bf16*)alloc((size_t)N * 256 * 2 > (size_t)E * 64 * 2
                              ? (size_t)N * 256 * 2 : (size_t)E * 64 * 2);
  float* logE4 = (float*)alloc((size_t)E * 4 * 4);
  float* logh  = (float*)alloc((size_t)EL * 4);
  size_t mN = (size_t)((N * 4 > E) ? N * 4 : E);
  float* mbuf  = (float*)alloc(mN * 4);
  float* sbuf  = (float*)alloc(mN * 4);

  dim3 blk(256);
  const unsigned tN = (N + 63) / 64, tEg = (E + 63) / 64, tELg = (EL + 63) / 64;
  const unsigned gE4 = (E + 3) / 4, gN4 = (N + 3) / 4;
  const unsigned cE = (E + 255) / 256, cEL = (EL + 255) / 256;
  const unsigned sE4 = (E * 4 + 255) / 256, sEL = (EL + 255) / 256, sE = cE;

  // ---- dtype detect + weights ----
  k_detect<<<dim3(1), blk, 0, stream>>>((const unsigned*)d_in[0], flag);
  WArgs wa;
  for (int i = 3; i <= 23; ++i) {
    wa.src[i - 3] = d_in[i];
    wa.beg[i - 3] = (int)wofs[i];
    wa.len[i - 3] = in_sizes[i];
  }
  wa.beg[21] = (int)wtot;
  k_cvt_all<<<dim3(512), blk, 0, stream>>>(wa, WA, (int)wtot, flag);

  // ---- CSR builds: dst->N (graph), ldst->E (line graph) ----
  int* deg = tmpi; int* cur = tmpi + E;
  k_izero<<<dim3(1024), blk, 0, stream>>>(tmpi, 2 * E);
  k_hist<<<dim3(cE), blk, 0, stream>>>(dst, deg, E);
  k_scan<<<dim3(1), dim3(1024), 0, stream>>>(deg, rpN, N);
  k_slot<<<dim3(cE), blk, 0, stream>>>(dst, rpN, cur, eidN, E);
  k_izero<<<dim3(1024), blk, 0, stream>>>(tmpi, 2 * E);
  k_hist<<<dim3(cEL), blk, 0, stream>>>(ldst, deg, EL);
  k_scan<<<dim3(1), dim3(1024), 0, stream>>>(deg, rpE, E);
  k_slot<<<dim3(cEL), blk, 0, stream>>>(ldst, rpE, cur, eidEL, EL);

  // ================= Phase 1: EGAT =================
  k_gmean<<<dim3((N + 1) / 2), dim3(128, 2), 0, stream>>>(d_in[1], 2, rpN, eidN,
                                                          aggB, N, 128, flag);
  k_mgemm2<<<dim3(tN, 4), blk, 0, stream>>>(d_in[0], 2, 128, WA + wofs[3], WA + wofs[4],
                                            8192, SA, SB, 256, N, flag);
  k_fill2<<<dim3(2048), blk, 0, stream>>>(mbuf, -INFINITY, (size_t)N * 4,
                                          sbuf, 0.0f, (size_t)N * 4);
  k_mcomb4<4><<<dim3(tEg), blk, 0, stream>>>(d_in[1], 2, WA + wofs[5], 8192,
      WA + wofs[9], WA + wofs[8], SA, SB, 256, src, dst, logE4, fedge, E, flag);
  k_seg_max4   <<<dim3(sE4), blk, 0, stream>>>(logE4, dst, mbuf, E);
  k_seg_expsum4<<<dim3(sE4), blk, 0, stream>>>(logE4, dst, mbuf, sbuf, E);
  // h = concat(nfeats, agg) @ e_Wnode^T + e_bnode  (all heads -> SA [N,256])
  k_mgemm<<<dim3(tN, 4), blk, 0, stream>>>(d_in[0], 2, 128, aggB, 0, 256,
      WA + wofs[6], 16384, WA + wofs[7], SA, 256, N, nullptr, nullptr, flag);
  k_ghnode<<<dim3(gN4), dim3(64, 4), 0, stream>>>(SA, logE4, sbuf, rpN, eidN, src, hnode, N);

  // ================= Phase 2: line-graph branch =================
  k_gmean<<<dim3(gE4), dim3(64, 4), 0, stream>>>(d_in[2], 2, rpE, eidEL, aggB, E, 64, flag);
  for (int h = 0; h < 4; ++h) {
    k_mgemm2<<<dim3(tEg), blk, 0, stream>>>(fedge, 0, 64,
        WA + wofs[10] + h * 4096, WA + wofs[11] + h * 4096, 0, SA, SB, 64, E, flag);
    k_fill2<<<dim3(2048), blk, 0, stream>>>(mbuf, -INFINITY, (size_t)E,
                                            sbuf, 0.0f, (size_t)E);
    k_mcomb<<<dim3(tELg), blk, 0, stream>>>(d_in[2], 2, 64,
        WA + wofs[12] + h * 4096, WA + wofs[16] + h * 64, WA + wofs[15] + h * 64,
        SA, SB, 64, lsrc, ldst, logh, EL, flag);
    k_seg_max1   <<<dim3(sEL), blk, 0, stream>>>(logh, ldst, mbuf, EL);
    k_seg_expsum1<<<dim3(sEL), blk, 0, stream>>>(logh, ldst, mbuf, sbuf, EL);
    k_mgemm<<<dim3(tEg, 1), blk, 0, stream>>>(fedge, 0, 64, aggB, 0, 128,
        WA + wofs[13] + (size_t)h * 8192, 0, WA + wofs[14] + h * 64,
        SA, 64, E, nullptr, nullptr, flag);
    k_gout2<<<dim3(gE4), dim3(64, 4), 0, stream>>>(SA, logh, sbuf, rpE, eidEL, lsrc,
                                                   outacc, E, h == 0 ? 1 : 0);
  }

  // ================= Phase 3: graph branch =================
  k_mgemm2<<<dim3(tN, 4), blk, 0, stream>>>(hnode, 0, 64, WA + wofs[17], WA + wofs[18],
                                            4096, SA, SB, 256, N, flag);
  k_fill2<<<dim3(2048), blk, 0, stream>>>(mbuf, -INFINITY, (size_t)N * 4,
                                          sbuf, 0.0f, (size_t)N * 4);
  k_mcomb4<2><<<dim3(tEg), blk, 0, stream>>>(fedge, 0, WA + wofs[19], 4096,
      WA + wofs[23], WA + wofs[22], SA, SB, 256, src, dst, logE4, nullptr, E, flag);
  k_seg_max4   <<<dim3(sE4), blk, 0, stream>>>(logE4, dst, mbuf, E);
  k_seg_expsum4<<<dim3(sE4), blk, 0, stream>>>(logE4, dst, mbuf, sbuf, E);
  for (int h = 0; h < 4; ++h) {
    k_mgemm<<<dim3(tEg, 1), blk, 0, stream>>>(hnode, 0, 64, fedge, 0, 128,
        WA + wofs[20] + (size_t)h * 8192, 0, WA + wofs[21] + h * 64,
        SB, 64, E, src, dst, flag);
    k_gout3<<<dim3(gE4), dim3(64, 4), 0, stream>>>(SB, logE4, sbuf, dst, rpE, eidEL, lsrc,
                                                   outacc, E, h);
  }

  k_cast<<<dim3(2048), blk, 0, stream>>>(d_out, outacc, (size_t)E * 64, flag);
}